// Round 1
// 962.206 us; speedup vs baseline: 1.2411x; 1.2411x over previous
//
#include <hip/hip_runtime.h>
#include <hip/hip_bf16.h>

// Shapes: B=512, S=128, D=128, HS=256, 4HS=1024, O=1.
// Pipeline (all bf16 MFMA, f32 accum):
//   prepw: WaT/VaT/WT transposed bf16 weights + U_eff packed into MFMA B-fragment order
//          where U_eff = U + fcW^T (x) Wy  (rank-1 fold of the y_prev@Wy recurrence term:
//          y_prev = h_prev@fcW^T + fc_b exactly for t>=1; t=0 correction applied in k_gx)
//   preph: H -> bf16 copy + per-b transpose HT[b][d][s]
//   k_att1: T1 = tanh(H @ Wa + ba)
//   k_att2: beta = softmax(T1 @ Va)
//   k_pool: poolT[t*512+b][d] = beta[b] @ H[b]
//   k_gx:   Gx = pool @ W + bias + fc_b*Wy (+ (y0-fc_b)*Wy at t==0), packed bf16 16B/lane
//   k_seq:  32 blocks x 16 batch rows, 128-step LSTM.
//           U residency: kc0-2,5,6 in VGPRs (160), kc3-4 in LDS (128KB, loaded once),
//           kc7 streamed from L2 with full-step prefetch distance.
//           Global h stores delayed one step so the barrier's vmcnt(0) drain is free.

using bf16x8 = __attribute__((ext_vector_type(8))) short;
using f32x4  = __attribute__((ext_vector_type(4))) float;

#define DEV static __device__ __forceinline__

DEV unsigned short f2bf(float x) {
    unsigned u = __float_as_uint(x);
    u += 0x7fffu + ((u >> 16) & 1u);          // round-to-nearest-even
    return (unsigned short)(u >> 16);
}
DEV float bf2f(unsigned short s) { return __uint_as_float(((unsigned)s) << 16); }
DEV float sigm(float x) { return 1.0f / (1.0f + __expf(-x)); }
DEV float tanh_f(float x) { float e = __expf(2.0f * x); return 1.0f - 2.0f / (e + 1.0f); }
DEV f32x4 mfma16(bf16x8 a, bf16x8 b, f32x4 c) {
    return __builtin_amdgcn_mfma_f32_16x16x32_bf16(a, b, c, 0, 0, 0);
}

// stage rows x 128 bf16 (row stride 128) into LDS with padded stride 136
DEV void stage128(const unsigned short* __restrict__ src, unsigned short* dst, int rows, int tid) {
    int chunks = rows * 16;
    for (int i = tid; i < chunks; i += 256) {
        int r = i >> 4, c = (i & 15) << 3;
        *(bf16x8*)(dst + r * 136 + c) = *(const bf16x8*)(src + r * 128 + c);
    }
}

// ---------------- prep kernels ----------------
__global__ void k_prepw(const float* __restrict__ Wa, const float* __restrict__ Va,
                        const float* __restrict__ W, const float* __restrict__ U,
                        const float* __restrict__ fcW, const float* __restrict__ Wy,
                        unsigned short* __restrict__ WaT, unsigned short* __restrict__ VaT,
                        unsigned short* __restrict__ WT, unsigned short* __restrict__ Upk) {
    int idx = blockIdx.x * 256 + threadIdx.x;
    if (idx < 16384) {
        int n = idx >> 7, k = idx & 127;
        WaT[idx] = f2bf(Wa[k * 128 + n]);
    } else if (idx < 32768) {
        int i = idx - 16384;
        int n = i >> 7, k = i & 127;
        VaT[i] = f2bf(Va[k * 128 + n]);
    } else if (idx < 163840) {
        int i = idx - 32768;
        int n = i >> 7, k = i & 127;
        WT[i] = f2bf(W[k * 1024 + n]);
    } else if (idx < 425984) {
        int i = idx - 163840;   // layout: ((((w*8+kc)*8+tt)*64+l)*8+j
        int j = i & 7, ll = (i >> 3) & 63, tt = (i >> 9) & 7, kc = (i >> 12) & 7, w = i >> 15;
        int k = kc * 32 + (ll >> 4) * 8 + j;
        int n = (tt >> 1) * 256 + w * 32 + (tt & 1) * 16 + (ll & 15);
        // rank-1 fold: U_eff = U + fcW^T Wy
        Upk[i] = f2bf(U[k * 1024 + n] + fcW[k] * Wy[n]);
    }
}

__global__ void k_preph(const float* __restrict__ H, unsigned short* __restrict__ Hbf,
                        unsigned short* __restrict__ HT) {
    for (size_t idx = (size_t)blockIdx.x * 256 + threadIdx.x; idx < 16777216u;
         idx += (size_t)gridDim.x * 256) {
        if (idx < 8388608u) {
            Hbf[idx] = f2bf(H[idx]);
        } else {
            size_t i = idx - 8388608u;
            int b = (int)(i >> 14);
            int rem = (int)(i & 16383);
            int d = rem >> 7, s = rem & 127;
            HT[i] = f2bf(H[((size_t)b * 128 + s) * 128 + d]);
        }
    }
}

// ---------------- T1 = tanh(H @ Wa + ba) ----------------
__global__ __launch_bounds__(256) void k_att1(const unsigned short* __restrict__ Hbf,
                                              const unsigned short* __restrict__ WaT,
                                              const float* __restrict__ ba,
                                              unsigned short* __restrict__ T1) {
    __shared__ unsigned short a_lds[64 * 136];
    __shared__ unsigned short b_lds[128 * 136];
    int tid = threadIdx.x;
    int m0 = blockIdx.x * 64;
    stage128(Hbf + (size_t)m0 * 128, a_lds, 64, tid);
    stage128(WaT, b_lds, 128, tid);
    __syncthreads();
    int w = tid >> 6, l = tid & 63, q = l >> 4, r = l & 15;
    f32x4 acc[8] = {};
    #pragma unroll
    for (int kc = 0; kc < 4; ++kc) {
        bf16x8 a = *(const bf16x8*)(a_lds + (w * 16 + r) * 136 + kc * 32 + q * 8);
        #pragma unroll
        for (int nt = 0; nt < 8; ++nt) {
            bf16x8 b = *(const bf16x8*)(b_lds + (nt * 16 + r) * 136 + kc * 32 + q * 8);
            acc[nt] = mfma16(a, b, acc[nt]);
        }
    }
    #pragma unroll
    for (int nt = 0; nt < 8; ++nt) {
        int col = nt * 16 + r;
        float bav = ba[col];
        #pragma unroll
        for (int j = 0; j < 4; ++j) {
            int row = m0 + w * 16 + q * 4 + j;
            T1[(size_t)row * 128 + col] = f2bf(tanh_f(acc[nt][j] + bav));
        }
    }
}

// ---------------- beta = softmax(T1 @ Va) ----------------
__global__ __launch_bounds__(256) void k_att2(const unsigned short* __restrict__ T1,
                                              const unsigned short* __restrict__ VaT,
                                              unsigned short* __restrict__ beta) {
    __shared__ __align__(16) char smem[52224];
    unsigned short* a_lds = (unsigned short*)smem;
    unsigned short* b_lds = (unsigned short*)(smem + 17408);
    float* lg  = (float*)smem;
    float* inv = (float*)(smem + 34048);
    int tid = threadIdx.x;
    int m0 = blockIdx.x * 64;
    stage128(T1 + (size_t)m0 * 128, a_lds, 64, tid);
    stage128(VaT, b_lds, 128, tid);
    __syncthreads();
    int w = tid >> 6, l = tid & 63, q = l >> 4, r = l & 15;
    f32x4 acc[8] = {};
    #pragma unroll
    for (int kc = 0; kc < 4; ++kc) {
        bf16x8 a = *(const bf16x8*)(a_lds + (w * 16 + r) * 136 + kc * 32 + q * 8);
        #pragma unroll
        for (int nt = 0; nt < 8; ++nt) {
            bf16x8 b = *(const bf16x8*)(b_lds + (nt * 16 + r) * 136 + kc * 32 + q * 8);
            acc[nt] = mfma16(a, b, acc[nt]);
        }
    }
    __syncthreads();
    #pragma unroll
    for (int nt = 0; nt < 8; ++nt)
        #pragma unroll
        for (int j = 0; j < 4; ++j)
            lg[(w * 16 + q * 4 + j) * 133 + nt * 16 + r] = acc[nt][j];
    __syncthreads();
    if (tid < 64) {
        float mx = -1e30f;
        for (int c = 0; c < 128; ++c) mx = fmaxf(mx, lg[tid * 133 + c]);
        float s = 0.f;
        for (int c = 0; c < 128; ++c) {
            float e = __expf(lg[tid * 133 + c] - mx);
            lg[tid * 133 + c] = e;
            s += e;
        }
        inv[tid] = 1.0f / s;
    }
    __syncthreads();
    for (int i = tid; i < 64 * 128; i += 256) {
        int rr = i >> 7, cc = i & 127;
        beta[(size_t)(m0 + rr) * 128 + cc] = f2bf(lg[rr * 133 + cc] * inv[rr]);
    }
}

// ---------------- poolT[t*512+b][d] = beta[b] @ H[b] ----------------
__global__ __launch_bounds__(256) void k_pool(const unsigned short* __restrict__ beta,
                                              const unsigned short* __restrict__ HT,
                                              unsigned short* __restrict__ poolT) {
    __shared__ unsigned short a_lds[64 * 136];
    __shared__ unsigned short b_lds[128 * 136];
    int tid = threadIdx.x;
    int b = blockIdx.x >> 1, mh = blockIdx.x & 1;
    stage128(beta + ((size_t)b * 128 + mh * 64) * 128, a_lds, 64, tid);
    stage128(HT + (size_t)b * 16384, b_lds, 128, tid);
    __syncthreads();
    int w = tid >> 6, l = tid & 63, q = l >> 4, r = l & 15;
    f32x4 acc[8] = {};
    #pragma unroll
    for (int kc = 0; kc < 4; ++kc) {
        bf16x8 a = *(const bf16x8*)(a_lds + (w * 16 + r) * 136 + kc * 32 + q * 8);
        #pragma unroll
        for (int nt = 0; nt < 8; ++nt) {
            bf16x8 bb = *(const bf16x8*)(b_lds + (nt * 16 + r) * 136 + kc * 32 + q * 8);
            acc[nt] = mfma16(a, bb, acc[nt]);
        }
    }
    #pragma unroll
    for (int nt = 0; nt < 8; ++nt)
        #pragma unroll
        for (int j = 0; j < 4; ++j) {
            int t = mh * 64 + w * 16 + q * 4 + j;
            poolT[((size_t)t * 512 + b) * 128 + nt * 16 + r] = f2bf(acc[nt][j]);
        }
}

// ---------------- Gx = pool @ W + bias + fc_b*Wy (+ (y0-fc_b)*Wy at t==0) ----------------
__global__ __launch_bounds__(256) void k_gx(const unsigned short* __restrict__ poolT,
                                            const unsigned short* __restrict__ WT,
                                            const float* __restrict__ bias,
                                            const float* __restrict__ Wy,
                                            const float* __restrict__ y0,
                                            const float* __restrict__ fcb,
                                            unsigned short* __restrict__ Gxp) {
    __shared__ unsigned short a_lds[64 * 136];
    __shared__ unsigned short b_lds[128 * 136];
    int tid = threadIdx.x;
    int mblk = blockIdx.x >> 3, nb = blockIdx.x & 7;
    int t = mblk >> 3, gblk = mblk & 7;
    int m0 = mblk * 64, n0 = nb * 128;
    stage128(poolT + (size_t)m0 * 128, a_lds, 64, tid);
    stage128(WT + (size_t)n0 * 128, b_lds, 128, tid);
    __syncthreads();
    int w = tid >> 6, l = tid & 63, q = l >> 4, r = l & 15;
    f32x4 acc[8] = {};
    #pragma unroll
    for (int kc = 0; kc < 4; ++kc) {
        bf16x8 a = *(const bf16x8*)(a_lds + (w * 16 + r) * 136 + kc * 32 + q * 8);
        #pragma unroll
        for (int nt = 0; nt < 8; ++nt) {
            bf16x8 bb = *(const bf16x8*)(b_lds + (nt * 16 + r) * 136 + kc * 32 + q * 8);
            acc[nt] = mfma16(a, bb, acc[nt]);
        }
    }
    int g_seq = gblk * 4 + w;   // wave's 16 rows = one sequential batch group
    float fcb0 = fcb[0];
    int bb0 = (mblk & 7) * 64 + w * 16 + q * 4;   // batch row of acc row j
    float yb[4];
    #pragma unroll
    for (int j = 0; j < 4; ++j)
        yb[j] = (t == 0) ? y0[bb0 + j] : fcb0;    // y-term scale at this t
    #pragma unroll
    for (int np2 = 0; np2 < 4; ++np2) {
        int nt0 = np2 * 2, nt1 = nt0 + 1;
        int col0 = n0 + nt0 * 16, col1 = n0 + nt1 * 16;
        float bv0 = bias[col0 + r], bv1 = bias[col1 + r];
        float wv0 = Wy[col0 + r],  wv1 = Wy[col1 + r];
        int w_seq = (col0 & 255) >> 5;
        int gate = col0 >> 8;
        size_t idx8 = ((((size_t)g_seq * 128 + t) * 8 + w_seq) * 4 + gate) * 64 + l;
        bf16x8 o;
        o[0] = (short)f2bf(acc[nt0][0] + bv0 + yb[0] * wv0);
        o[1] = (short)f2bf(acc[nt0][1] + bv0 + yb[1] * wv0);
        o[2] = (short)f2bf(acc[nt0][2] + bv0 + yb[2] * wv0);
        o[3] = (short)f2bf(acc[nt0][3] + bv0 + yb[3] * wv0);
        o[4] = (short)f2bf(acc[nt1][0] + bv1 + yb[0] * wv1);
        o[5] = (short)f2bf(acc[nt1][1] + bv1 + yb[1] * wv1);
        o[6] = (short)f2bf(acc[nt1][2] + bv1 + yb[2] * wv1);
        o[7] = (short)f2bf(acc[nt1][3] + bv1 + yb[3] * wv1);
        *(bf16x8*)(Gxp + idx8 * 8) = o;   // 16B/lane, lane-contiguous
    }
}

// ---------------- sequential LSTM: 32 blocks x 16 batch rows ----------------
// dynamic LDS: U kc3-4 (131072 B) | h frag-order dbuf (16384 B) | ypart (512 B)
__global__ __launch_bounds__(512, 2) void k_seq(const unsigned short* __restrict__ Gxp,
                                                const unsigned short* __restrict__ Upk,
                                                const float* __restrict__ fcW,
                                                const float* __restrict__ fcb,
                                                float* __restrict__ out) {
    extern __shared__ __align__(16) char dynbuf[];
    unsigned short* u2   = (unsigned short*)dynbuf;             // 65536 shorts (kc3,4)
    unsigned short* h_fl = (unsigned short*)(dynbuf + 131072);  // 2 x 4096 shorts
    float* ypart         = (float*)(dynbuf + 147456);           // [8][16], last step only

    int tid = threadIdx.x;
    int g = blockIdx.x;
    int w = tid >> 6, l = tid & 63, q = l >> 4, r = l & 15;
    float fc_b0 = fcb[0];

    // register-resident U_eff: kc 0,1,2,5,6 (160 VGPRs)
    bf16x8 u_res[5][8];
    {
        const bf16x8* up = (const bf16x8*)Upk;
        const int kcs[5] = {0, 1, 2, 5, 6};
        #pragma unroll
        for (int i = 0; i < 5; ++i)
            #pragma unroll
            for (int tt = 0; tt < 8; ++tt)
                u_res[i][tt] = up[((w * 8 + kcs[i]) * 8 + tt) * 64 + l];
    }

    // LDS-resident U_eff: kc 3..4 (each lane copies its own fragment -> conflict-free b128)
    #pragma unroll
    for (int kcL = 0; kcL < 2; ++kcL)
        #pragma unroll
        for (int tt = 0; tt < 8; ++tt) {
            size_t gofs = (size_t)(((w * 8 + 3 + kcL) * 8 + tt) * 64 + l) * 8;
            size_t lofs = (size_t)(((w * 2 + kcL) * 8 + tt) * 64 + l) * 8;
            *(bf16x8*)(u2 + lofs) = *(const bf16x8*)(Upk + gofs);
        }

    float fw[2];
    fw[0] = fcW[w * 32 + r];
    fw[1] = fcW[w * 32 + 16 + r];
    float c_st[2][4] = {};
    float hv_st[2][4] = {};   // previous step's h (f32), stored to global one step late

    for (int i = tid; i < 4096; i += 512) h_fl[i] = 0;   // h(0) = 0, frag-order buf 0
    __syncthreads();

    // per-lane pointers (loop-invariant bases; step stride folded in)
    const bf16x8* gq  = (const bf16x8*)Gxp + (size_t)g * 262144 + w * 256 + l;  // +2048/step
    const bf16x8* u7p = (const bf16x8*)Upk + (w * 8 + 7) * 512 + l;             // kc7 stream
    float* outp = out + 512 + (size_t)(g * 16 + q * 4) * 32768 + w * 32 + r;    // +256/step

    for (int t = 0; t < 128; ++t) {
        int p = t & 1, np = p ^ 1;
        unsigned short* hp = h_fl + p * 4096;
        unsigned short* hn = h_fl + np * 4096;

        // ---- delayed global store of previous step's h (full step to retire
        //      before this step's barrier drains vmcnt(0)) ----
        if (t > 0) {
            #pragma unroll
            for (int sub = 0; sub < 2; ++sub)
                #pragma unroll
                for (int j = 0; j < 4; ++j)
                    outp[(size_t)j * 32768 + sub * 16] = hv_st[sub][j];
            outp += 256;
        }

        // ---- streamed U kc7: issued at step top, consumed last (full-phase cover) ----
        bf16x8 u7[8];
        #pragma unroll
        for (int tt = 0; tt < 8; ++tt) u7[tt] = u7p[tt * 64];

        // ---- Gx prefetch (4x dwordx4), consumed at cell math ----
        bf16x8 gxq[4];
        #pragma unroll
        for (int gate = 0; gate < 4; ++gate) gxq[gate] = gq[gate * 64];

        // ---- MFMA: gates partial = h_prev @ U_eff (y-term folded into U_eff) ----
        f32x4 acc[8] = {};
        #pragma unroll
        for (int i = 0; i < 3; ++i) {          // reg kc 0..2
            bf16x8 a = *(const bf16x8*)(hp + ((i * 4 + q) * 16 + r) * 8);
            #pragma unroll
            for (int tt = 0; tt < 8; ++tt) acc[tt] = mfma16(a, u_res[i][tt], acc[tt]);
        }
        #pragma unroll
        for (int kcL = 0; kcL < 2; ++kcL) {    // LDS kc 3..4
            bf16x8 a = *(const bf16x8*)(hp + (((3 + kcL) * 4 + q) * 16 + r) * 8);
            #pragma unroll
            for (int tt = 0; tt < 8; ++tt) {
                bf16x8 u = *(const bf16x8*)(u2 + (size_t)(((w * 2 + kcL) * 8 + tt) * 64 + l) * 8);
                acc[tt] = mfma16(a, u, acc[tt]);
            }
        }
        #pragma unroll
        for (int i = 0; i < 2; ++i) {          // reg kc 5..6
            bf16x8 a = *(const bf16x8*)(hp + (((5 + i) * 4 + q) * 16 + r) * 8);
            #pragma unroll
            for (int tt = 0; tt < 8; ++tt) acc[tt] = mfma16(a, u_res[3 + i][tt], acc[tt]);
        }
        {                                      // streamed kc7
            bf16x8 a = *(const bf16x8*)(hp + ((7 * 4 + q) * 16 + r) * 8);
            #pragma unroll
            for (int tt = 0; tt < 8; ++tt) acc[tt] = mfma16(a, u7[tt], acc[tt]);
        }

        // ---- LSTM cell ----
        float ypj[4] = {0.f, 0.f, 0.f, 0.f};
        #pragma unroll
        for (int sub = 0; sub < 2; ++sub) {
            #pragma unroll
            for (int j = 0; j < 4; ++j) {
                float iv = sigm(acc[0 + sub][j] + bf2f((unsigned short)gxq[0][sub * 4 + j]));
                float fv = sigm(acc[2 + sub][j] + bf2f((unsigned short)gxq[1][sub * 4 + j]));
                float gv = tanh_f(acc[4 + sub][j] + bf2f((unsigned short)gxq[2][sub * 4 + j]));
                float ov = sigm(acc[6 + sub][j] + bf2f((unsigned short)gxq[3][sub * 4 + j]));
                float c = fv * c_st[sub][j] + iv * gv;
                c_st[sub][j] = c;
                float hv = ov * tanh_f(c);
                int row = q * 4 + j;
                // h write in A-fragment order: kc=w, qd=sub*2+(r>>3), elem=r&7
                hn[((w * 4 + sub * 2 + (r >> 3)) * 16 + row) * 8 + (r & 7)] = f2bf(hv);
                hv_st[sub][j] = hv;
                ypj[j] += hv * fw[sub];
            }
        }
        if (t == 127) {   // final y = fc(h_127) + fc_b, exact f32 path
            #pragma unroll
            for (int j = 0; j < 4; ++j) {
                float v = ypj[j];
                v += __shfl_xor(v, 1);
                v += __shfl_xor(v, 2);
                v += __shfl_xor(v, 4);
                v += __shfl_xor(v, 8);
                if (r == 0) ypart[w * 16 + q * 4 + j] = v;
            }
        }
        gq += 2048;
        __syncthreads();
    }

    // final step's h store
    #pragma unroll
    for (int sub = 0; sub < 2; ++sub)
        #pragma unroll
        for (int j = 0; j < 4; ++j)
            outp[(size_t)j * 32768 + sub * 16] = hv_st[sub][j];

    if (tid < 16) {
        float y = fc_b0;
        #pragma unroll
        for (int ww = 0; ww < 8; ++ww) y += ypart[ww * 16 + tid];
        out[g * 16 + tid] = y;
    }
}

extern "C" void kernel_launch(void* const* d_in, const int* in_sizes, int n_in,
                              void* d_out, int out_size, void* d_ws, size_t ws_size,
                              hipStream_t stream) {
    const float* H    = (const float*)d_in[0];
    const float* y0   = (const float*)d_in[1];
    const float* Wa   = (const float*)d_in[2];
    // d_in[3] = Ua: multiplied by an all-zero state in the reference -> unused
    const float* ba   = (const float*)d_in[4];
    const float* Va   = (const float*)d_in[5];
    const float* W    = (const float*)d_in[6];
    const float* U    = (const float*)d_in[7];
    const float* bias = (const float*)d_in[8];
    const float* Wy   = (const float*)d_in[9];
    const float* fcW  = (const float*)d_in[10];
    const float* fcb  = (const float*)d_in[11];
    float* out = (float*)d_out;
    char* ws = (char*)d_ws;

    unsigned short* Hbf   = (unsigned short*)(ws);
    unsigned short* HT    = (unsigned short*)(ws + 16777216);
    unsigned short* T1    = (unsigned short*)(ws + 2 * 16777216);
    unsigned short* beta  = (unsigned short*)(ws + 3 * 16777216);
    unsigned short* poolT = (unsigned short*)(ws + 4 * 16777216);
    unsigned short* Gxp   = (unsigned short*)(ws + (size_t)5 * 16777216);        // 134.2 MB
    unsigned short* WaT   = (unsigned short*)(ws + (size_t)5 * 16777216 + 134217728);
    unsigned short* VaT   = WaT + 16384;
    unsigned short* WT    = VaT + 16384;
    unsigned short* Upk   = WT + 131072;

    hipFuncSetAttribute((const void*)k_seq, hipFuncAttributeMaxDynamicSharedMemorySize, 147968);

    hipLaunchKernelGGL(k_prepw, dim3(1664), dim3(256), 0, stream, Wa, Va, W, U, fcW, Wy,
                       WaT, VaT, WT, Upk);
    hipLaunchKernelGGL(k_preph, dim3(8192), dim3(256), 0, stream, H, Hbf, HT);
    hipLaunchKernelGGL(k_att1, dim3(1024), dim3(256), 0, stream, Hbf, WaT, ba, T1);
    hipLaunchKernelGGL(k_att2, dim3(1024), dim3(256), 0, stream, T1, VaT, beta);
    hipLaunchKernelGGL(k_pool, dim3(1024), dim3(256), 0, stream, beta, HT, poolT);
    hipLaunchKernelGGL(k_gx, dim3(8192), dim3(256), 0, stream, poolT, WT, bias, Wy, y0, fcb, Gxp);
    hipLaunchKernelGGL(k_seq, dim3(32), dim3(512), 147968, stream, Gxp, Upk, fcW, fcb, out);
}

// Round 2
// 622.794 us; speedup vs baseline: 1.9175x; 1.5450x over previous
//
#include <hip/hip_runtime.h>
#include <hip/hip_bf16.h>

// Shapes: B=512, S=128, D=128, HS=256, 4HS=1024, O=1.
// Pipeline (all bf16 MFMA, f32 accum):
//   prepw: WaT/VaT/WT transposed bf16 weights + U_eff packed into MFMA B-fragment order
//          where U_eff = U + fcW^T (x) Wy  (rank-1 fold of the y_prev@Wy recurrence term)
//   prept: H -> per-b LDS-tiled transpose HT[b][d][s] (bf16), coalesced both sides
//   k_att1: T1 = tanh(H @ Wa + ba)   (stages H f32 -> bf16 directly)
//   k_att2: beta = softmax(T1 @ Va)
//   k_pool: poolT[t*512+b][d] = beta[b] @ H[b]
//   k_gx:   Gx = pool @ W + bias + fc_b*Wy (+ (y0-fc_b)*Wy at t==0),
//           packed [g64][t][w][gate][lane64][j4] bf16 (8B/lane)
//   k_seq:  64 blocks x 8 batch rows (M=8 in an M=16 MFMA; rows 8-15 zero).
//           After MFMA, gates are redistributed via __shfl so all 64 lanes do
//           cell math on 4 valid h-values -> per-CU transcendental work halves
//           and spreads over 2x the CUs.
//           U residency: kc0-2,5,6 in VGPRs, kc3-4 in LDS, kc7 streamed.
//           Global h stores delayed one step so the barrier vmcnt(0) drain is free.

using bf16x8 = __attribute__((ext_vector_type(8))) short;
using f32x4  = __attribute__((ext_vector_type(4))) float;
using u16x4  = __attribute__((ext_vector_type(4))) unsigned short;

#define DEV static __device__ __forceinline__

DEV unsigned short f2bf(float x) {
    unsigned u = __float_as_uint(x);
    u += 0x7fffu + ((u >> 16) & 1u);          // round-to-nearest-even
    return (unsigned short)(u >> 16);
}
DEV float bf2f(unsigned short s) { return __uint_as_float(((unsigned)s) << 16); }
DEV float sigm(float x) { return 1.0f / (1.0f + __expf(-x)); }
DEV float tanh_f(float x) { float e = __expf(2.0f * x); return 1.0f - 2.0f / (e + 1.0f); }
DEV f32x4 mfma16(bf16x8 a, bf16x8 b, f32x4 c) {
    return __builtin_amdgcn_mfma_f32_16x16x32_bf16(a, b, c, 0, 0, 0);
}

// stage rows x 128 bf16 (row stride 128) into LDS with padded stride 136
DEV void stage128(const unsigned short* __restrict__ src, unsigned short* dst, int rows, int tid) {
    int chunks = rows * 16;
    for (int i = tid; i < chunks; i += 256) {
        int r = i >> 4, c = (i & 15) << 3;
        *(bf16x8*)(dst + r * 136 + c) = *(const bf16x8*)(src + r * 128 + c);
    }
}
// stage rows x 128 f32 -> bf16 LDS (stride 136)
DEV void stage128f(const float* __restrict__ src, unsigned short* dst, int rows, int tid) {
    int chunks = rows * 16;
    for (int i = tid; i < chunks; i += 256) {
        int r = i >> 4, c = (i & 15) << 3;
        const float* s = src + r * 128 + c;
        bf16x8 o;
        #pragma unroll
        for (int e = 0; e < 8; ++e) o[e] = (short)f2bf(s[e]);
        *(bf16x8*)(dst + r * 136 + c) = o;
    }
}

// ---------------- prep kernels ----------------
__global__ void k_prepw(const float* __restrict__ Wa, const float* __restrict__ Va,
                        const float* __restrict__ W, const float* __restrict__ U,
                        const float* __restrict__ fcW, const float* __restrict__ Wy,
                        unsigned short* __restrict__ WaT, unsigned short* __restrict__ VaT,
                        unsigned short* __restrict__ WT, unsigned short* __restrict__ Upk) {
    int idx = blockIdx.x * 256 + threadIdx.x;
    if (idx < 16384) {
        int n = idx >> 7, k = idx & 127;
        WaT[idx] = f2bf(Wa[k * 128 + n]);
    } else if (idx < 32768) {
        int i = idx - 16384;
        int n = i >> 7, k = i & 127;
        VaT[i] = f2bf(Va[k * 128 + n]);
    } else if (idx < 163840) {
        int i = idx - 32768;
        int n = i >> 7, k = i & 127;
        WT[i] = f2bf(W[k * 1024 + n]);
    } else if (idx < 425984) {
        int i = idx - 163840;   // layout: ((((w*8+kc)*8+tt)*64+l)*8+j
        int j = i & 7, ll = (i >> 3) & 63, tt = (i >> 9) & 7, kc = (i >> 12) & 7, w = i >> 15;
        int k = kc * 32 + (ll >> 4) * 8 + j;
        int n = (tt >> 1) * 256 + w * 32 + (tt & 1) * 16 + (ll & 15);
        // rank-1 fold: U_eff = U + fcW^T Wy
        Upk[i] = f2bf(U[k * 1024 + n] + fcW[k] * Wy[n]);
    }
}

// per-b LDS-tiled transpose: HT[b][d][s] (bf16). Coalesced global load + store,
// LDS pad 130 shorts -> conflict-free transposed reads.
__global__ __launch_bounds__(256) void k_prept(const float* __restrict__ H,
                                               unsigned short* __restrict__ HT) {
    __shared__ unsigned short tl[128 * 130];
    int b = blockIdx.x, tid = threadIdx.x;
    const float* Hb = H + (size_t)b * 16384;
    for (int i = tid; i < 16384; i += 256) {
        int s = i >> 7, d = i & 127;
        tl[s * 130 + d] = f2bf(Hb[i]);
    }
    __syncthreads();
    unsigned short* HTb = HT + (size_t)b * 16384;
    for (int i = tid; i < 16384; i += 256) {
        int d = i >> 7, s = i & 127;
        HTb[i] = tl[s * 130 + d];
    }
}

// ---------------- T1 = tanh(H @ Wa + ba) ----------------
__global__ __launch_bounds__(256) void k_att1(const float* __restrict__ H,
                                              const unsigned short* __restrict__ WaT,
                                              const float* __restrict__ ba,
                                              unsigned short* __restrict__ T1) {
    __shared__ unsigned short a_lds[64 * 136];
    __shared__ unsigned short b_lds[128 * 136];
    int tid = threadIdx.x;
    int m0 = blockIdx.x * 64;
    stage128f(H + (size_t)m0 * 128, a_lds, 64, tid);
    stage128(WaT, b_lds, 128, tid);
    __syncthreads();
    int w = tid >> 6, l = tid & 63, q = l >> 4, r = l & 15;
    f32x4 acc[8] = {};
    #pragma unroll
    for (int kc = 0; kc < 4; ++kc) {
        bf16x8 a = *(const bf16x8*)(a_lds + (w * 16 + r) * 136 + kc * 32 + q * 8);
        #pragma unroll
        for (int nt = 0; nt < 8; ++nt) {
            bf16x8 b = *(const bf16x8*)(b_lds + (nt * 16 + r) * 136 + kc * 32 + q * 8);
            acc[nt] = mfma16(a, b, acc[nt]);
        }
    }
    #pragma unroll
    for (int nt = 0; nt < 8; ++nt) {
        int col = nt * 16 + r;
        float bav = ba[col];
        #pragma unroll
        for (int j = 0; j < 4; ++j) {
            int row = m0 + w * 16 + q * 4 + j;
            T1[(size_t)row * 128 + col] = f2bf(tanh_f(acc[nt][j] + bav));
        }
    }
}

// ---------------- beta = softmax(T1 @ Va) ----------------
__global__ __launch_bounds__(256) void k_att2(const unsigned short* __restrict__ T1,
                                              const unsigned short* __restrict__ VaT,
                                              unsigned short* __restrict__ beta) {
    __shared__ __align__(16) char smem[52224];
    unsigned short* a_lds = (unsigned short*)smem;
    unsigned short* b_lds = (unsigned short*)(smem + 17408);
    float* lg  = (float*)smem;
    float* inv = (float*)(smem + 34048);
    int tid = threadIdx.x;
    int m0 = blockIdx.x * 64;
    stage128(T1 + (size_t)m0 * 128, a_lds, 64, tid);
    stage128(VaT, b_lds, 128, tid);
    __syncthreads();
    int w = tid >> 6, l = tid & 63, q = l >> 4, r = l & 15;
    f32x4 acc[8] = {};
    #pragma unroll
    for (int kc = 0; kc < 4; ++kc) {
        bf16x8 a = *(const bf16x8*)(a_lds + (w * 16 + r) * 136 + kc * 32 + q * 8);
        #pragma unroll
        for (int nt = 0; nt < 8; ++nt) {
            bf16x8 b = *(const bf16x8*)(b_lds + (nt * 16 + r) * 136 + kc * 32 + q * 8);
            acc[nt] = mfma16(a, b, acc[nt]);
        }
    }
    __syncthreads();
    #pragma unroll
    for (int nt = 0; nt < 8; ++nt)
        #pragma unroll
        for (int j = 0; j < 4; ++j)
            lg[(w * 16 + q * 4 + j) * 133 + nt * 16 + r] = acc[nt][j];
    __syncthreads();
    if (tid < 64) {
        float mx = -1e30f;
        for (int c = 0; c < 128; ++c) mx = fmaxf(mx, lg[tid * 133 + c]);
        float s = 0.f;
        for (int c = 0; c < 128; ++c) {
            float e = __expf(lg[tid * 133 + c] - mx);
            lg[tid * 133 + c] = e;
            s += e;
        }
        inv[tid] = 1.0f / s;
    }
    __syncthreads();
    for (int i = tid; i < 64 * 128; i += 256) {
        int rr = i >> 7, cc = i & 127;
        beta[(size_t)(m0 + rr) * 128 + cc] = f2bf(lg[rr * 133 + cc] * inv[rr]);
    }
}

// ---------------- poolT[t*512+b][d] = beta[b] @ H[b] ----------------
__global__ __launch_bounds__(256) void k_pool(const unsigned short* __restrict__ beta,
                                              const unsigned short* __restrict__ HT,
                                              unsigned short* __restrict__ poolT) {
    __shared__ unsigned short a_lds[64 * 136];
    __shared__ unsigned short b_lds[128 * 136];
    int tid = threadIdx.x;
    int b = blockIdx.x >> 1, mh = blockIdx.x & 1;
    stage128(beta + ((size_t)b * 128 + mh * 64) * 128, a_lds, 64, tid);
    stage128(HT + (size_t)b * 16384, b_lds, 128, tid);
    __syncthreads();
    int w = tid >> 6, l = tid & 63, q = l >> 4, r = l & 15;
    f32x4 acc[8] = {};
    #pragma unroll
    for (int kc = 0; kc < 4; ++kc) {
        bf16x8 a = *(const bf16x8*)(a_lds + (w * 16 + r) * 136 + kc * 32 + q * 8);
        #pragma unroll
        for (int nt = 0; nt < 8; ++nt) {
            bf16x8 bb = *(const bf16x8*)(b_lds + (nt * 16 + r) * 136 + kc * 32 + q * 8);
            acc[nt] = mfma16(a, bb, acc[nt]);
        }
    }
    #pragma unroll
    for (int nt = 0; nt < 8; ++nt)
        #pragma unroll
        for (int j = 0; j < 4; ++j) {
            int t = mh * 64 + w * 16 + q * 4 + j;
            poolT[((size_t)t * 512 + b) * 128 + nt * 16 + r] = f2bf(acc[nt][j]);
        }
}

// ---------------- Gx = pool @ W + bias + y-term, packed [g64][t][w][gate][lane][j4] ----------------
__global__ __launch_bounds__(256) void k_gx(const unsigned short* __restrict__ poolT,
                                            const unsigned short* __restrict__ WT,
                                            const float* __restrict__ bias,
                                            const float* __restrict__ Wy,
                                            const float* __restrict__ y0,
                                            const float* __restrict__ fcb,
                                            unsigned short* __restrict__ Gxp) {
    __shared__ unsigned short a_lds[64 * 136];
    __shared__ unsigned short b_lds[128 * 136];
    int tid = threadIdx.x;
    int mblk = blockIdx.x >> 3, nb = blockIdx.x & 7;
    int m0 = mblk * 64, n0 = nb * 128;
    stage128(poolT + (size_t)m0 * 128, a_lds, 64, tid);
    stage128(WT + (size_t)n0 * 128, b_lds, 128, tid);
    __syncthreads();
    int w = tid >> 6, l = tid & 63, q = l >> 4, r = l & 15;
    f32x4 acc[8] = {};
    #pragma unroll
    for (int kc = 0; kc < 4; ++kc) {
        bf16x8 a = *(const bf16x8*)(a_lds + (w * 16 + r) * 136 + kc * 32 + q * 8);
        #pragma unroll
        for (int nt = 0; nt < 8; ++nt) {
            bf16x8 bb = *(const bf16x8*)(b_lds + (nt * 16 + r) * 136 + kc * 32 + q * 8);
            acc[nt] = mfma16(a, bb, acc[nt]);
        }
    }
    int t = mblk >> 3;
    int gate = nb >> 1;
    int g_hi = (mblk & 7) * 8 + w * 2 + (q >> 1);   // batch group (of 8) for this lane
    float fcb0 = fcb[0];
    int bb0 = (mblk & 7) * 64 + w * 16 + q * 4;     // global batch row of acc row j
    float yb[4];
    #pragma unroll
    for (int j = 0; j < 4; ++j)
        yb[j] = (t == 0) ? y0[bb0 + j] : fcb0;      // y-term scale at this t
    #pragma unroll
    for (int nt = 0; nt < 8; ++nt) {
        int col = n0 + nt * 16 + r;
        float bv = bias[col], wv = Wy[col];
        int w_seq = (nb & 1) * 4 + (nt >> 1);       // k_seq wave owning this 32-col slice
        int l_seq = (nt & 1) * 32 + (q & 1) * 16 + r;
        size_t base = (((((size_t)g_hi * 128 + t) * 8 + w_seq) * 4 + gate) * 64 + l_seq) * 4;
        u16x4 o;
        o[0] = f2bf(acc[nt][0] + bv + yb[0] * wv);
        o[1] = f2bf(acc[nt][1] + bv + yb[1] * wv);
        o[2] = f2bf(acc[nt][2] + bv + yb[2] * wv);
        o[3] = f2bf(acc[nt][3] + bv + yb[3] * wv);
        *(u16x4*)(Gxp + base) = o;   // 8B/lane, 256B-contiguous per 32 lanes
    }
}

// ---------------- sequential LSTM: 64 blocks x 8 batch rows ----------------
// dynamic LDS: U kc3-4 (131072 B) | h frag-order dbuf (16384 B) | ypart (256 B)
__global__ __launch_bounds__(512, 2) void k_seq(const unsigned short* __restrict__ Gxp,
                                                const unsigned short* __restrict__ Upk,
                                                const float* __restrict__ fcW,
                                                const float* __restrict__ fcb,
                                                float* __restrict__ out) {
    extern __shared__ __align__(16) char dynbuf[];
    unsigned short* u2   = (unsigned short*)dynbuf;             // 65536 shorts (kc3,4)
    unsigned short* h_fl = (unsigned short*)(dynbuf + 131072);  // 2 x 4096 shorts
    float* ypart         = (float*)(dynbuf + 147456);           // [8][8], last step only

    int tid = threadIdx.x;
    int g = blockIdx.x;                 // batch group of 8 rows
    int w = tid >> 6, l = tid & 63, q = l >> 4, r = l & 15;
    int qlow = q & 1, colsub = q >> 1;
    float fc_b0 = fcb[0];

    // register-resident U_eff: kc 0,1,2,5,6
    bf16x8 u_res[5][8];
    {
        const bf16x8* up = (const bf16x8*)Upk;
        const int kcs[5] = {0, 1, 2, 5, 6};
        #pragma unroll
        for (int i = 0; i < 5; ++i)
            #pragma unroll
            for (int tt = 0; tt < 8; ++tt)
                u_res[i][tt] = up[((w * 8 + kcs[i]) * 8 + tt) * 64 + l];
    }

    // LDS-resident U_eff: kc 3..4
    #pragma unroll
    for (int kcL = 0; kcL < 2; ++kcL)
        #pragma unroll
        for (int tt = 0; tt < 8; ++tt) {
            size_t gofs = (size_t)(((w * 8 + 3 + kcL) * 8 + tt) * 64 + l) * 8;
            size_t lofs = (size_t)(((w * 2 + kcL) * 8 + tt) * 64 + l) * 8;
            *(bf16x8*)(u2 + lofs) = *(const bf16x8*)(Upk + gofs);
        }

    float fw0 = fcW[w * 32 + colsub * 16 + r];
    float c_st[4] = {};
    float hv_st[4] = {};   // previous step's h (f32), stored to global one step late

    for (int i = tid; i < 8192; i += 512) h_fl[i] = 0;   // h(0)=0 AND rows 8-15 of both bufs
    __syncthreads();

    // per-lane pointers
    const unsigned short* gxp = Gxp + ((((size_t)g * 128 * 8 + w) * 4) * 64 + l) * 4; // +8192/t
    const bf16x8* u7p = (const bf16x8*)Upk + (w * 8 + 7) * 512 + l;                    // kc7 stream
    float* outp = out + 512 + (size_t)(g * 8 + qlow * 4) * 32768 + w * 32 + colsub * 16 + r;
    int srcl = l & 31;

    for (int t = 0; t < 128; ++t) {
        int p = t & 1, np = p ^ 1;
        unsigned short* hp = h_fl + p * 4096;
        unsigned short* hn = h_fl + np * 4096;

        // ---- delayed global store of previous step's h ----
        if (t > 0) {
            #pragma unroll
            for (int j = 0; j < 4; ++j)
                outp[(size_t)j * 32768] = hv_st[j];
            outp += 256;
        }

        // ---- streamed U kc7: issued at step top, consumed last ----
        bf16x8 u7[8];
        #pragma unroll
        for (int tt = 0; tt < 8; ++tt) u7[tt] = u7p[tt * 64];

        // ---- Gx prefetch (4x 8B), consumed at cell math ----
        u16x4 gxv[4];
        #pragma unroll
        for (int gate = 0; gate < 4; ++gate)
            gxv[gate] = *(const u16x4*)(gxp + gate * 256);

        // ---- MFMA: gates partial = h_prev @ U_eff ----
        f32x4 acc[8] = {};
        #pragma unroll
        for (int i = 0; i < 3; ++i) {          // reg kc 0..2
            bf16x8 a = *(const bf16x8*)(hp + ((i * 4 + q) * 16 + r) * 8);
            #pragma unroll
            for (int tt = 0; tt < 8; ++tt) acc[tt] = mfma16(a, u_res[i][tt], acc[tt]);
        }
        #pragma unroll
        for (int kcL = 0; kcL < 2; ++kcL) {    // LDS kc 3..4
            bf16x8 a = *(const bf16x8*)(hp + (((3 + kcL) * 4 + q) * 16 + r) * 8);
            #pragma unroll
            for (int tt = 0; tt < 8; ++tt) {
                bf16x8 u = *(const bf16x8*)(u2 + (size_t)(((w * 2 + kcL) * 8 + tt) * 64 + l) * 8);
                acc[tt] = mfma16(a, u, acc[tt]);
            }
        }
        #pragma unroll
        for (int i = 0; i < 2; ++i) {          // reg kc 5..6
            bf16x8 a = *(const bf16x8*)(hp + (((5 + i) * 4 + q) * 16 + r) * 8);
            #pragma unroll
            for (int tt = 0; tt < 8; ++tt) acc[tt] = mfma16(a, u_res[3 + i][tt], acc[tt]);
        }
        {                                      // streamed kc7
            bf16x8 a = *(const bf16x8*)(hp + ((7 * 4 + q) * 16 + r) * 8);
            #pragma unroll
            for (int tt = 0; tt < 8; ++tt) acc[tt] = mfma16(a, u7[tt], acc[tt]);
        }

        // ---- redistribute gates: valid rows live in lanes q<2; give upper half
        //      (q>=2) the colsub=1 slice so every lane does 4 h-values ----
        float av[4][4];
        #pragma unroll
        for (int gp = 0; gp < 4; ++gp)
            #pragma unroll
            for (int j = 0; j < 4; ++j) {
                float lo = acc[2 * gp][j];
                float mh = __shfl(acc[2 * gp + 1][j], srcl);
                av[gp][j] = (l < 32) ? lo : mh;
            }

        // ---- LSTM cell: 4 values/lane, rows qlow*4+j, col w*32+colsub*16+r ----
        float ypj[4];
        #pragma unroll
        for (int j = 0; j < 4; ++j) {
            float iv = sigm(av[0][j] + bf2f(gxv[0][j]));
            float fv = sigm(av[1][j] + bf2f(gxv[1][j]));
            float gv = tanh_f(av[2][j] + bf2f(gxv[2][j]));
            float ov = sigm(av[3][j] + bf2f(gxv[3][j]));
            float c = fv * c_st[j] + iv * gv;
            c_st[j] = c;
            float hv = ov * tanh_f(c);
            int rl = qlow * 4 + j;
            // h write in A-fragment order: kc=w, qd=colsub*2+(r>>3), elem=r&7
            hn[((w * 4 + colsub * 2 + (r >> 3)) * 16 + rl) * 8 + (r & 7)] = f2bf(hv);
            hv_st[j] = hv;
            ypj[j] = hv * fw0;
        }
        if (t == 127) {   // final y = fc(h_127) + fc_b, exact f32 path
            #pragma unroll
            for (int j = 0; j < 4; ++j) {
                float v = ypj[j];
                v += __shfl_xor(v, 1);
                v += __shfl_xor(v, 2);
                v += __shfl_xor(v, 4);
                v += __shfl_xor(v, 8);
                v += __shfl_xor(v, 32);        // combine colsub 0/1 (same qlow)
                if (r == 0 && q < 2) ypart[w * 8 + qlow * 4 + j] = v;
            }
        }
        gxp += 8192;
        __syncthreads();
    }

    // final step's h store
    #pragma unroll
    for (int j = 0; j < 4; ++j)
        outp[(size_t)j * 32768] = hv_st[j];

    if (tid < 8) {
        float y = fc_b0;
        #pragma unroll
        for (int ww = 0; ww < 8; ++ww) y += ypart[ww * 8 + tid];
        out[g * 8 + tid] = y;
    }
}

extern "C" void kernel_launch(void* const* d_in, const int* in_sizes, int n_in,
                              void* d_out, int out_size, void* d_ws, size_t ws_size,
                              hipStream_t stream) {
    const float* H    = (const float*)d_in[0];
    const float* y0   = (const float*)d_in[1];
    const float* Wa   = (const float*)d_in[2];
    // d_in[3] = Ua: multiplied by an all-zero state in the reference -> unused
    const float* ba   = (const float*)d_in[4];
    const float* Va   = (const float*)d_in[5];
    const float* W    = (const float*)d_in[6];
    const float* U    = (const float*)d_in[7];
    const float* bias = (const float*)d_in[8];
    const float* Wy   = (const float*)d_in[9];
    const float* fcW  = (const float*)d_in[10];
    const float* fcb  = (const float*)d_in[11];
    float* out = (float*)d_out;
    char* ws = (char*)d_ws;

    unsigned short* HT    = (unsigned short*)(ws + 16777216);
    unsigned short* T1    = (unsigned short*)(ws + 2 * 16777216);
    unsigned short* beta  = (unsigned short*)(ws + 3 * 16777216);
    unsigned short* poolT = (unsigned short*)(ws + 4 * 16777216);
    unsigned short* Gxp   = (unsigned short*)(ws + (size_t)5 * 16777216);        // 134.2 MB
    unsigned short* WaT   = (unsigned short*)(ws + (size_t)5 * 16777216 + 134217728);
    unsigned short* VaT   = WaT + 16384;
    unsigned short* WT    = VaT + 16384;
    unsigned short* Upk   = WT + 131072;

    hipFuncSetAttribute((const void*)k_seq, hipFuncAttributeMaxDynamicSharedMemorySize, 147968);

    hipLaunchKernelGGL(k_prepw, dim3(1664), dim3(256), 0, stream, Wa, Va, W, U, fcW, Wy,
                       WaT, VaT, WT, Upk);
    hipLaunchKernelGGL(k_prept, dim3(512), dim3(256), 0, stream, H, HT);
    hipLaunchKernelGGL(k_att1, dim3(1024), dim3(256), 0, stream, H, WaT, ba, T1);
    hipLaunchKernelGGL(k_att2, dim3(1024), dim3(256), 0, stream, T1, VaT, beta);
    hipLaunchKernelGGL(k_pool, dim3(1024), dim3(256), 0, stream, beta, HT, poolT);
    hipLaunchKernelGGL(k_gx, dim3(8192), dim3(256), 0, stream, poolT, WT, bias, Wy, y0, fcb, Gxp);
    hipLaunchKernelGGL(k_seq, dim3(64), dim3(512), 147968, stream, Gxp, Upk, fcW, fcb, out);
}

// Round 3
// 517.892 us; speedup vs baseline: 2.3060x; 1.2026x over previous
//
#include <hip/hip_runtime.h>
#include <hip/hip_bf16.h>

// Shapes: B=512, S=128, D=128, HS=256, 4HS=1024, O=1.
// Pipeline (all bf16 MFMA, f32 accum):
//   prepw: WaT/VaT/WT transposed bf16 weights + U_eff packed into MFMA B-fragment order
//          where U_eff = U + fcW^T (x) Wy  (rank-1 fold of the y_prev@Wy recurrence term)
//   prept: H -> per-b LDS-tiled transpose HT[b][d][s] (bf16)
//   k_att:  FUSED per-b: T1 = tanh(H_b@Wa+ba); beta = softmax(T1@Va) (in-register,
//           wave-parallel); pool_b = beta@H_b. 2 LDS buffers ping-ponged over 3 MFMA
//           phases; poolT layout [b][t][d].
//   k_gx:   Gx = pool @ W + bias + fc_b*Wy (+ (y0-fc_b)*Wy at t==0),
//           packed [g128][t][w8][gate4][lane64][jj2] bf16
//   k_seq:  128 blocks x 4 batch rows (M=4 in an M=16 MFMA; rows 4-15 zero via a
//           shared zero row). Post-MFMA per-wave LDS scratch exchange redistributes
//           gates so all 64 lanes do cell math on 2 h-values.
//           U residency: kc0-2,5,6 in VGPRs, kc3-4 in LDS, kc7 streamed.
//           Global h stores delayed one step so the barrier vmcnt(0) drain is free.

using bf16x8 = __attribute__((ext_vector_type(8))) short;
using f32x4  = __attribute__((ext_vector_type(4))) float;

#define DEV static __device__ __forceinline__

DEV unsigned short f2bf(float x) {
    unsigned u = __float_as_uint(x);
    u += 0x7fffu + ((u >> 16) & 1u);          // round-to-nearest-even
    return (unsigned short)(u >> 16);
}
DEV float bf2f(unsigned short s) { return __uint_as_float(((unsigned)s) << 16); }
DEV float sigm(float x) { return 1.0f / (1.0f + __expf(-x)); }
DEV float tanh_f(float x) { float e = __expf(2.0f * x); return 1.0f - 2.0f / (e + 1.0f); }
DEV f32x4 mfma16(bf16x8 a, bf16x8 b, f32x4 c) {
    return __builtin_amdgcn_mfma_f32_16x16x32_bf16(a, b, c, 0, 0, 0);
}

// stage rows x 128 bf16 (row stride 128) into LDS with padded stride 136
DEV void stage128(const unsigned short* __restrict__ src, unsigned short* dst, int rows, int tid) {
    int chunks = rows * 16;
    for (int i = tid; i < chunks; i += 256) {
        int r = i >> 4, c = (i & 15) << 3;
        *(bf16x8*)(dst + r * 136 + c) = *(const bf16x8*)(src + r * 128 + c);
    }
}
// stage rows x 128 f32 -> bf16 LDS (stride 136)
DEV void stage128f(const float* __restrict__ src, unsigned short* dst, int rows, int tid) {
    int chunks = rows * 16;
    for (int i = tid; i < chunks; i += 256) {
        int r = i >> 4, c = (i & 15) << 3;
        const float* s = src + r * 128 + c;
        bf16x8 o;
        #pragma unroll
        for (int e = 0; e < 8; ++e) o[e] = (short)f2bf(s[e]);
        *(bf16x8*)(dst + r * 136 + c) = o;
    }
}

// ---------------- prep kernels ----------------
__global__ void k_prepw(const float* __restrict__ Wa, const float* __restrict__ Va,
                        const float* __restrict__ W, const float* __restrict__ U,
                        const float* __restrict__ fcW, const float* __restrict__ Wy,
                        unsigned short* __restrict__ WaT, unsigned short* __restrict__ VaT,
                        unsigned short* __restrict__ WT, unsigned short* __restrict__ Upk) {
    int idx = blockIdx.x * 256 + threadIdx.x;
    if (idx < 16384) {
        int n = idx >> 7, k = idx & 127;
        WaT[idx] = f2bf(Wa[k * 128 + n]);
    } else if (idx < 32768) {
        int i = idx - 16384;
        int n = i >> 7, k = i & 127;
        VaT[i] = f2bf(Va[k * 128 + n]);
    } else if (idx < 163840) {
        int i = idx - 32768;
        int n = i >> 7, k = i & 127;
        WT[i] = f2bf(W[k * 1024 + n]);
    } else if (idx < 425984) {
        int i = idx - 163840;   // layout: ((((w*8+kc)*8+tt)*64+l)*8+j
        int j = i & 7, ll = (i >> 3) & 63, tt = (i >> 9) & 7, kc = (i >> 12) & 7, w = i >> 15;
        int k = kc * 32 + (ll >> 4) * 8 + j;
        int n = (tt >> 1) * 256 + w * 32 + (tt & 1) * 16 + (ll & 15);
        // rank-1 fold: U_eff = U + fcW^T Wy
        Upk[i] = f2bf(U[k * 1024 + n] + fcW[k] * Wy[n]);
    }
}

// per-b LDS-tiled transpose: HT[b][d][s] (bf16)
__global__ __launch_bounds__(256) void k_prept(const float* __restrict__ H,
                                               unsigned short* __restrict__ HT) {
    __shared__ unsigned short tl[128 * 130];
    int b = blockIdx.x, tid = threadIdx.x;
    const float* Hb = H + (size_t)b * 16384;
    for (int i = tid; i < 16384; i += 256) {
        int s = i >> 7, d = i & 127;
        tl[s * 130 + d] = f2bf(Hb[i]);
    }
    __syncthreads();
    unsigned short* HTb = HT + (size_t)b * 16384;
    for (int i = tid; i < 16384; i += 256) {
        int d = i >> 7, s = i & 127;
        HTb[i] = tl[s * 130 + d];
    }
}

// ---------------- FUSED attention: T1 -> softmax -> pool, one block per b ----------------
__global__ __launch_bounds__(256) void k_att(const float* __restrict__ H,
                                             const unsigned short* __restrict__ WaT,
                                             const unsigned short* __restrict__ VaT,
                                             const unsigned short* __restrict__ HT,
                                             const float* __restrict__ ba,
                                             unsigned short* __restrict__ poolT) {
    __shared__ unsigned short A1[128 * 136];
    __shared__ unsigned short B1[128 * 136];
    int tid = threadIdx.x, b = blockIdx.x;
    int w = tid >> 6, l = tid & 63, q = l >> 4, r = l & 15;

    // phase 1: T1 = tanh(H_b @ WaT + ba)
    stage128f(H + (size_t)b * 16384, A1, 128, tid);
    stage128(WaT, B1, 128, tid);
    __syncthreads();
    f32x4 acc[2][8] = {};
    #pragma unroll
    for (int kc = 0; kc < 4; ++kc)
        #pragma unroll
        for (int mt = 0; mt < 2; ++mt) {
            bf16x8 a = *(const bf16x8*)(A1 + (w * 32 + mt * 16 + r) * 136 + kc * 32 + q * 8);
            #pragma unroll
            for (int nt = 0; nt < 8; ++nt) {
                bf16x8 bb = *(const bf16x8*)(B1 + (nt * 16 + r) * 136 + kc * 32 + q * 8);
                acc[mt][nt] = mfma16(a, bb, acc[mt][nt]);
            }
        }
    __syncthreads();
    // T1 -> B1 (bf16, A-layout); VaT -> A1
    #pragma unroll
    for (int nt = 0; nt < 8; ++nt) {
        float bav = ba[nt * 16 + r];
        #pragma unroll
        for (int mt = 0; mt < 2; ++mt)
            #pragma unroll
            for (int j = 0; j < 4; ++j)
                B1[(w * 32 + mt * 16 + q * 4 + j) * 136 + nt * 16 + r] =
                    f2bf(tanh_f(acc[mt][nt][j] + bav));
    }
    stage128(VaT, A1, 128, tid);
    __syncthreads();

    // phase 2: logits = T1 @ VaT, softmax in-register
    f32x4 lacc[2][8] = {};
    #pragma unroll
    for (int kc = 0; kc < 4; ++kc)
        #pragma unroll
        for (int mt = 0; mt < 2; ++mt) {
            bf16x8 a = *(const bf16x8*)(B1 + (w * 32 + mt * 16 + r) * 136 + kc * 32 + q * 8);
            #pragma unroll
            for (int nt = 0; nt < 8; ++nt) {
                bf16x8 bb = *(const bf16x8*)(A1 + (nt * 16 + r) * 136 + kc * 32 + q * 8);
                lacc[mt][nt] = mfma16(a, bb, lacc[mt][nt]);
            }
        }
    float inv_[2][4];
    #pragma unroll
    for (int mt = 0; mt < 2; ++mt)
        #pragma unroll
        for (int j = 0; j < 4; ++j) {
            float mx = lacc[mt][0][j];
            #pragma unroll
            for (int nt = 1; nt < 8; ++nt) mx = fmaxf(mx, lacc[mt][nt][j]);
            mx = fmaxf(mx, __shfl_xor(mx, 1));
            mx = fmaxf(mx, __shfl_xor(mx, 2));
            mx = fmaxf(mx, __shfl_xor(mx, 4));
            mx = fmaxf(mx, __shfl_xor(mx, 8));
            float s = 0.f;
            #pragma unroll
            for (int nt = 0; nt < 8; ++nt) {
                float e = __expf(lacc[mt][nt][j] - mx);
                lacc[mt][nt][j] = e;
                s += e;
            }
            s += __shfl_xor(s, 1);
            s += __shfl_xor(s, 2);
            s += __shfl_xor(s, 4);
            s += __shfl_xor(s, 8);
            inv_[mt][j] = 1.0f / s;
        }
    __syncthreads();
    // beta -> B1; HT_b -> A1
    #pragma unroll
    for (int mt = 0; mt < 2; ++mt)
        #pragma unroll
        for (int nt = 0; nt < 8; ++nt)
            #pragma unroll
            for (int j = 0; j < 4; ++j)
                B1[(w * 32 + mt * 16 + q * 4 + j) * 136 + nt * 16 + r] =
                    f2bf(lacc[mt][nt][j] * inv_[mt][j]);
    stage128(HT + (size_t)b * 16384, A1, 128, tid);
    __syncthreads();

    // phase 3: pool = beta @ HT_b -> poolT[b][t][d]
    f32x4 pacc[2][8] = {};
    #pragma unroll
    for (int kc = 0; kc < 4; ++kc)
        #pragma unroll
        for (int mt = 0; mt < 2; ++mt) {
            bf16x8 a = *(const bf16x8*)(B1 + (w * 32 + mt * 16 + r) * 136 + kc * 32 + q * 8);
            #pragma unroll
            for (int nt = 0; nt < 8; ++nt) {
                bf16x8 bb = *(const bf16x8*)(A1 + (nt * 16 + r) * 136 + kc * 32 + q * 8);
                pacc[mt][nt] = mfma16(a, bb, pacc[mt][nt]);
            }
        }
    unsigned short* pb = poolT + (size_t)b * 16384;
    #pragma unroll
    for (int mt = 0; mt < 2; ++mt)
        #pragma unroll
        for (int nt = 0; nt < 8; ++nt)
            #pragma unroll
            for (int j = 0; j < 4; ++j)
                pb[(w * 32 + mt * 16 + q * 4 + j) * 128 + nt * 16 + r] = f2bf(pacc[mt][nt][j]);
}

// ---------------- Gx = pool @ W + bias + y-term, packed [g128][t][w][gate][l][jj2] ----------------
__global__ __launch_bounds__(256) void k_gx(const unsigned short* __restrict__ poolT,
                                            const unsigned short* __restrict__ WT,
                                            const float* __restrict__ bias,
                                            const float* __restrict__ Wy,
                                            const float* __restrict__ y0,
                                            const float* __restrict__ fcb,
                                            unsigned short* __restrict__ Gxp) {
    __shared__ unsigned short a_lds[64 * 136];
    __shared__ unsigned short b_lds[128 * 136];
    int tid = threadIdx.x;
    int mblk = blockIdx.x >> 3, nb = blockIdx.x & 7;
    int b = mblk >> 1, t0 = (mblk & 1) * 64, n0 = nb * 128;
    stage128(poolT + (size_t)b * 16384 + t0 * 128, a_lds, 64, tid);
    stage128(WT + (size_t)n0 * 128, b_lds, 128, tid);
    __syncthreads();
    int w = tid >> 6, l = tid & 63, q = l >> 4, r = l & 15;
    f32x4 acc[8] = {};
    #pragma unroll
    for (int kc = 0; kc < 4; ++kc) {
        bf16x8 a = *(const bf16x8*)(a_lds + (w * 16 + r) * 136 + kc * 32 + q * 8);
        #pragma unroll
        for (int nt = 0; nt < 8; ++nt) {
            bf16x8 bb = *(const bf16x8*)(b_lds + (nt * 16 + r) * 136 + kc * 32 + q * 8);
            acc[nt] = mfma16(a, bb, acc[nt]);
        }
    }
    int g = b >> 2, rg = b & 3;
    float fcb0 = fcb[0];
    float y00 = y0[b];
    #pragma unroll
    for (int nt = 0; nt < 8; ++nt) {
        int col = n0 + nt * 16 + r;
        float bv = bias[col], wv = Wy[col];
        int c = col & 255;
        int w_s = c >> 5, cbit = (c >> 4) & 1;
        int l_s = ((rg & 2) | cbit) * 16 + r;
        int gate = col >> 8;
        size_t base = (size_t)g * 524288 + (size_t)w_s * 512 + (size_t)gate * 128 +
                      l_s * 2 + (rg & 1);
        #pragma unroll
        for (int j = 0; j < 4; ++j) {
            int t = t0 + w * 16 + q * 4 + j;
            float yb = (t == 0) ? y00 : fcb0;
            Gxp[base + (size_t)t * 4096] = f2bf(acc[nt][j] + bv + yb * wv);
        }
    }
}

// ---------------- sequential LSTM: 128 blocks x 4 batch rows ----------------
// dynbuf: U kc3-4 (131072) | h 5-row-slot dbuf (5120) | scr (16384) | ypart (128)
__global__ __launch_bounds__(512, 2) void k_seq(const unsigned short* __restrict__ Gxp,
                                                const unsigned short* __restrict__ Upk,
                                                const float* __restrict__ fcW,
                                                const float* __restrict__ fcb,
                                                float* __restrict__ out) {
    extern __shared__ __align__(16) char dynbuf[];
    unsigned short* u2   = (unsigned short*)dynbuf;             // 65536 shorts (kc3,4)
    unsigned short* h_fl = (unsigned short*)(dynbuf + 131072);  // 2 x 1280 shorts
    float* scr           = (float*)(dynbuf + 136192);           // [8w][8tt][16r] f32x4
    float* ypart         = (float*)(dynbuf + 152576);           // [8][4]

    int tid = threadIdx.x;
    int g = blockIdx.x;                 // batch group of 4 rows
    int w = tid >> 6, l = tid & 63, q = l >> 4, r = l & 15;
    int rr = (r < 4) ? r : 4;           // A-frag row; 4 = shared zero row
    float fc_b0 = fcb[0];

    // register-resident U_eff: kc 0,1,2,5,6
    bf16x8 u_res[5][8];
    {
        const bf16x8* up = (const bf16x8*)Upk;
        const int kcs[5] = {0, 1, 2, 5, 6};
        #pragma unroll
        for (int i = 0; i < 5; ++i)
            #pragma unroll
            for (int tt = 0; tt < 8; ++tt)
                u_res[i][tt] = up[((w * 8 + kcs[i]) * 8 + tt) * 64 + l];
    }
    // LDS-resident U_eff: kc 3..4
    #pragma unroll
    for (int kcL = 0; kcL < 2; ++kcL)
        #pragma unroll
        for (int tt = 0; tt < 8; ++tt) {
            size_t gofs = (size_t)(((w * 8 + 3 + kcL) * 8 + tt) * 64 + l) * 8;
            size_t lofs = (size_t)(((w * 2 + kcL) * 8 + tt) * 64 + l) * 8;
            *(bf16x8*)(u2 + lofs) = *(const bf16x8*)(Upk + gofs);
        }

    float fw0 = fcW[w * 32 + ((q & 1) << 4) + r];
    float c_st[2] = {}, hv_st[2] = {};

    for (int i = tid; i < 2560; i += 512) h_fl[i] = 0;   // h(0)=0, zero rows stay zero
    __syncthreads();

    // per-lane pointers
    const unsigned short* gxp = Gxp + (size_t)g * 524288 + w * 512 + l * 2;   // +4096/t
    const bf16x8* u7p = (const bf16x8*)Upk + (w * 8 + 7) * 512 + l;           // kc7 stream
    // b = g*4 + (q&2) + jj; col = w*32 + (q&1)*16 + r
    float* outp = out + 512 + (size_t)(g * 4 + (q & 2)) * 32768 + w * 32 + ((q & 1) << 4) + r;

    for (int t = 0; t < 128; ++t) {
        unsigned short* hp = h_fl + (t & 1) * 1280;
        unsigned short* hn = h_fl + ((t & 1) ^ 1) * 1280;

        // ---- delayed global store of previous step's h ----
        if (t > 0) {
            outp[0] = hv_st[0];
            outp[32768] = hv_st[1];
            outp += 256;
        }

        // ---- streamed U kc7: issued at step top, consumed last ----
        bf16x8 u7[8];
        #pragma unroll
        for (int tt = 0; tt < 8; ++tt) u7[tt] = u7p[tt * 64];

        // ---- Gx prefetch: 4 gates x 2 bf16 (dword each) ----
        unsigned gxv[4];
        #pragma unroll
        for (int gp = 0; gp < 4; ++gp) gxv[gp] = *(const unsigned*)(gxp + gp * 128);

        // ---- MFMA: gates partial = h_prev @ U_eff ----
        f32x4 acc[8] = {};
        #pragma unroll
        for (int i = 0; i < 3; ++i) {          // reg kc 0..2
            bf16x8 a = *(const bf16x8*)(hp + ((i * 4 + q) * 5 + rr) * 8);
            #pragma unroll
            for (int tt = 0; tt < 8; ++tt) acc[tt] = mfma16(a, u_res[i][tt], acc[tt]);
        }
        #pragma unroll
        for (int kcL = 0; kcL < 2; ++kcL) {    // LDS kc 3..4
            bf16x8 a = *(const bf16x8*)(hp + (((3 + kcL) * 4 + q) * 5 + rr) * 8);
            #pragma unroll
            for (int tt = 0; tt < 8; ++tt) {
                bf16x8 u = *(const bf16x8*)(u2 + (size_t)(((w * 2 + kcL) * 8 + tt) * 64 + l) * 8);
                acc[tt] = mfma16(a, u, acc[tt]);
            }
        }
        #pragma unroll
        for (int i = 0; i < 2; ++i) {          // reg kc 5..6
            bf16x8 a = *(const bf16x8*)(hp + (((5 + i) * 4 + q) * 5 + rr) * 8);
            #pragma unroll
            for (int tt = 0; tt < 8; ++tt) acc[tt] = mfma16(a, u_res[3 + i][tt], acc[tt]);
        }
        {                                      // streamed kc7
            bf16x8 a = *(const bf16x8*)(hp + ((7 * 4 + q) * 5 + rr) * 8);
            #pragma unroll
            for (int tt = 0; tt < 8; ++tt) acc[tt] = mfma16(a, u7[tt], acc[tt]);
        }

        // ---- per-wave scratch exchange: q==0 lanes hold the 4 valid rows ----
        if (q == 0) {
            #pragma unroll
            for (int tt = 0; tt < 8; ++tt)
                *(f32x4*)(scr + ((w * 8 + tt) * 16 + r) * 4) = acc[tt];
        }
        asm volatile("s_waitcnt lgkmcnt(0)" ::: "memory");
        __builtin_amdgcn_sched_barrier(0);
        float av[4][2];
        #pragma unroll
        for (int gp = 0; gp < 4; ++gp) {
            const float* p = scr + ((w * 8 + gp * 2 + (q & 1)) * 16 + r) * 4 + (q & 2);
            av[gp][0] = p[0];
            av[gp][1] = p[1];
        }

        // ---- LSTM cell: 2 values/lane, rows (q&2)+jj, col w*32+(q&1)*16+r ----
        float ypj[2];
        #pragma unroll
        for (int jj = 0; jj < 2; ++jj) {
            int sh = jj * 16;
            float iv = sigm(av[0][jj] + bf2f((unsigned short)(gxv[0] >> sh)));
            float fv = sigm(av[1][jj] + bf2f((unsigned short)(gxv[1] >> sh)));
            float gv = tanh_f(av[2][jj] + bf2f((unsigned short)(gxv[2] >> sh)));
            float ov = sigm(av[3][jj] + bf2f((unsigned short)(gxv[3] >> sh)));
            float c = fv * c_st[jj] + iv * gv;
            c_st[jj] = c;
            float hv = ov * tanh_f(c);
            int row = (q & 2) + jj;
            // h write in A-fragment order: slot = kc(w)*4 + qd, 5-row slots
            hn[((w * 4 + ((q & 1) << 1) + (r >> 3)) * 5 + row) * 8 + (r & 7)] = f2bf(hv);
            hv_st[jj] = hv;
            ypj[jj] = hv * fw0;
        }
        if (t == 127) {   // final y = fc(h_127) + fc_b, exact f32 path
            #pragma unroll
            for (int jj = 0; jj < 2; ++jj) {
                float v = ypj[jj];
                v += __shfl_xor(v, 1);
                v += __shfl_xor(v, 2);
                v += __shfl_xor(v, 4);
                v += __shfl_xor(v, 8);
                v += __shfl_xor(v, 16);        // combine (q&1) column halves
                if (r == 0 && !(q & 1)) ypart[w * 4 + (q & 2) + jj] = v;
            }
        }
        gxp += 4096;
        __syncthreads();
    }

    // final step's h store
    outp[0] = hv_st[0];
    outp[32768] = hv_st[1];

    if (tid < 4) {
        float y = fc_b0;
        #pragma unroll
        for (int ww = 0; ww < 8; ++ww) y += ypart[ww * 4 + tid];
        out[g * 4 + tid] = y;
    }
}

extern "C" void kernel_launch(void* const* d_in, const int* in_sizes, int n_in,
                              void* d_out, int out_size, void* d_ws, size_t ws_size,
                              hipStream_t stream) {
    const float* H    = (const float*)d_in[0];
    const float* y0   = (const float*)d_in[1];
    const float* Wa   = (const float*)d_in[2];
    // d_in[3] = Ua: multiplied by an all-zero state in the reference -> unused
    const float* ba   = (const float*)d_in[4];
    const float* Va   = (const float*)d_in[5];
    const float* W    = (const float*)d_in[6];
    const float* U    = (const float*)d_in[7];
    const float* bias = (const float*)d_in[8];
    const float* Wy   = (const float*)d_in[9];
    const float* fcW  = (const float*)d_in[10];
    const float* fcb  = (const float*)d_in[11];
    float* out = (float*)d_out;
    char* ws = (char*)d_ws;

    unsigned short* HT    = (unsigned short*)(ws);                      // 16.8 MB
    unsigned short* poolT = (unsigned short*)(ws + 16777216);           // 16.8 MB, [b][t][d]
    unsigned short* Gxp   = (unsigned short*)(ws + 2 * 16777216);       // 134.2 MB
    unsigned short* WaT   = (unsigned short*)(ws + 2 * 16777216 + 134217728);
    unsigned short* VaT   = WaT + 16384;
    unsigned short* WT    = VaT + 16384;
    unsigned short* Upk   = WT + 131072;

    hipFuncSetAttribute((const void*)k_seq, hipFuncAttributeMaxDynamicSharedMemorySize, 152704);

    hipLaunchKernelGGL(k_prepw, dim3(1664), dim3(256), 0, stream, Wa, Va, W, U, fcW, Wy,
                       WaT, VaT, WT, Upk);
    hipLaunchKernelGGL(k_prept, dim3(512), dim3(256), 0, stream, H, HT);
    hipLaunchKernelGGL(k_att, dim3(512), dim3(256), 0, stream, H, WaT, VaT, HT, ba, poolT);
    hipLaunchKernelGGL(k_gx, dim3(8192), dim3(256), 0, stream, poolT, WT, bias, Wy, y0, fcb, Gxp);
    hipLaunchKernelGGL(k_seq, dim3(128), dim3(512), 152704, stream, Gxp, Upk, fcW, fcb, out);
}